// Round 1
// baseline (109.481 us; speedup 1.0000x reference)
//
#include <hip/hip_runtime.h>
#include <hip/hip_bf16.h>

#define Bn   32
#define HWn  676
#define Cn   768
#define Mn   32
#define NC   200
#define KT   (Mn*Cn)      // 24576
#define Sn   8
#define CHUNK 85          // ceil(676/8); last chunk = 81

#define LOGITS_OFF 0
#define ATTN_OFF   (Bn*NC)                 // 6400
#define EMB_OFF    (ATTN_OFF + Bn*HWn*Mn)  // 698624

// ---------------- zero init (logits, norm accum, optionally emb) -------------
__global__ __launch_bounds__(256) void z_kernel(float* __restrict__ out,
                                                float* __restrict__ norm_acc,
                                                int zero_emb) {
    int i = blockIdx.x * 256 + threadIdx.x;
    if (i < Bn * NC) out[LOGITS_OFF + i] = 0.f;
    if (i < Bn) norm_acc[i] = 0.f;
    if (zero_emb && i < Bn * KT) out[EMB_OFF + i] = 0.f;
}

// ---------------- fused: attention maps + split-K bilinear pooling -----------
// grid = B*S = 256 blocks (1 per CU), 768 threads.
__global__ __launch_bounds__(768, 1) void f_kernel(const float* __restrict__ f6,
                                                   const float* __restrict__ f7,
                                                   const float* __restrict__ wA,
                                                   float* __restrict__ attn_out,
                                                   float* __restrict__ part,
                                                   float* __restrict__ emb_atomic,
                                                   int partial_mode) {
    __shared__ float wS[Cn * Mn];       // 96 KB
    __shared__ float attnS[CHUNK * Mn]; // 10.6 KB

    const int tid = threadIdx.x;
    const int blk = blockIdx.x;
    const int b = blk >> 3;
    const int s = blk & 7;
    const int p0 = s * CHUNK;
    const int np = min(HWn - p0, CHUNK);

    // stage w_attn (C,M) into LDS, float4-coalesced
    {
        const float4* src = reinterpret_cast<const float4*>(wA);
        float4* dst = reinterpret_cast<float4*>(wS);
        #pragma unroll
        for (int i = tid; i < Cn * Mn / 4; i += 768) dst[i] = src[i];
    }
    __syncthreads();

    // ---- phase 1: attention rows. thread = (position-slot, 4 m's) ----
    const int m4 = tid & 7;   // m-group: m = m4*4 .. +3
    const int pg = tid >> 3;  // 0..95 position slots
    if (pg < np) {
        const int p = p0 + pg;
        const float4* x4p = reinterpret_cast<const float4*>(f7 + ((size_t)b * HWn + p) * Cn);
        float a0 = 0.f, a1 = 0.f, a2 = 0.f, a3 = 0.f;
        #pragma unroll 4
        for (int c4 = 0; c4 < Cn / 4; ++c4) {
            float4 x = x4p[c4];
            const float* wb = &wS[c4 * 4 * Mn + m4 * 4];
            float4 w0 = *reinterpret_cast<const float4*>(wb);
            float4 w1 = *reinterpret_cast<const float4*>(wb + Mn);
            float4 w2 = *reinterpret_cast<const float4*>(wb + 2 * Mn);
            float4 w3 = *reinterpret_cast<const float4*>(wb + 3 * Mn);
            a0 += x.x * w0.x + x.y * w1.x + x.z * w2.x + x.w * w3.x;
            a1 += x.x * w0.y + x.y * w1.y + x.z * w2.y + x.w * w3.y;
            a2 += x.x * w0.z + x.y * w1.z + x.z * w2.z + x.w * w3.z;
            a3 += x.x * w0.w + x.y * w1.w + x.z * w2.w + x.w * w3.w;
        }
        float4 r; r.x = a0; r.y = a1; r.z = a2; r.w = a3;
        *reinterpret_cast<float4*>(&attnS[pg * Mn + m4 * 4]) = r;
        *reinterpret_cast<float4*>(attn_out + ((size_t)(b * HWn + p)) * Mn + m4 * 4) = r;
    }
    __syncthreads();

    // ---- phase 2: bilinear pooling partial, thread = one channel c ----
    float acc[Mn];
    #pragma unroll
    for (int m = 0; m < Mn; ++m) acc[m] = 0.f;

    const float* f6b = f6 + ((size_t)b * HWn + p0) * Cn + tid;
    for (int pl = 0; pl < np; ++pl) {
        float x = f6b[(size_t)pl * Cn];  // coalesced across the 768 threads
        const float4* ar = reinterpret_cast<const float4*>(&attnS[pl * Mn]); // broadcast
        #pragma unroll
        for (int mq = 0; mq < 8; ++mq) {
            float4 a = ar[mq];
            acc[4 * mq + 0] += a.x * x;
            acc[4 * mq + 1] += a.y * x;
            acc[4 * mq + 2] += a.z * x;
            acc[4 * mq + 3] += a.w * x;
        }
    }

    if (partial_mode) {
        float* pdst = part + ((size_t)(b * Sn + s)) * KT + tid;
        #pragma unroll
        for (int m = 0; m < Mn; ++m) pdst[m * Cn] = acc[m];
    } else {
        float* edst = emb_atomic + (size_t)b * KT + tid;
        #pragma unroll
        for (int m = 0; m < Mn; ++m) atomicAdd(edst + m * Cn, acc[m]);
    }
}

// ---------------- reduce split-K, signed sqrt, norm partial ------------------
// grid = B*8 = 256 blocks, 256 threads. block = (b, m-group of 4)
__global__ __launch_bounds__(256) void r_kernel(const float* __restrict__ part,
                                                float* __restrict__ emb,
                                                float* __restrict__ norm_acc,
                                                int partial_mode) {
    const int tid = threadIdx.x;
    const int b = blockIdx.x >> 3;
    const int mg = blockIdx.x & 7;
    float lsq = 0.f;
    #pragma unroll
    for (int r = 0; r < 12; ++r) {
        int e = r * 256 + tid;      // 0..3071 within this m-group
        int ml = e / Cn;
        int c = e - ml * Cn;
        int m = mg * 4 + ml;
        size_t off = (size_t)m * Cn + c;
        float sum;
        if (partial_mode) {
            sum = 0.f;
            #pragma unroll
            for (int s2 = 0; s2 < Sn; ++s2) sum += part[((size_t)(b * Sn + s2)) * KT + off];
        } else {
            sum = emb[(size_t)b * KT + off];  // raw atomic-accumulated sum
        }
        float v = sum * (1.0f / (float)HWn);
        float ssq = copysignf(sqrtf(fabsf(v) + 1e-12f), v);
        emb[(size_t)b * KT + off] = ssq;
        lsq += ssq * ssq;
    }
    // block reduction of lsq
    #pragma unroll
    for (int o = 32; o > 0; o >>= 1) lsq += __shfl_down(lsq, o, 64);
    __shared__ float rb[4];
    if ((tid & 63) == 0) rb[tid >> 6] = lsq;
    __syncthreads();
    if (tid == 0) atomicAdd(&norm_acc[b], rb[0] + rb[1] + rb[2] + rb[3]);
}

// ---------------- normalize embeddings ---------------------------------------
__global__ __launch_bounds__(256) void n_kernel(float* __restrict__ emb,
                                                const float* __restrict__ norm_acc) {
    const int b = blockIdx.x >> 3;
    const int g = blockIdx.x & 7;
    float scale = rsqrtf(fmaxf(norm_acc[b], 1e-12f));
    float* p = emb + (size_t)b * KT + g * 3072 + threadIdx.x;
    #pragma unroll
    for (int r = 0; r < 12; ++r) p[r * 256] *= scale;
}

// ---------------- classifier: k-split, all 32 batches per block ---------------
// grid = KT/96 = 256 blocks, 256 threads. thread = one class n (<200).
__global__ __launch_bounds__(256) void l_kernel(const float* __restrict__ emb,
                                                const float* __restrict__ wC,
                                                float* __restrict__ logits) {
    __shared__ float eS[Bn * 96];  // 12 KB: emb chunk *100 for all 32 batches
    const int tid = threadIdx.x;
    const int k0 = blockIdx.x * 96;
    for (int i = tid; i < Bn * 96; i += 256) {
        int b = i / 96;
        int k = i - b * 96;
        eS[i] = emb[(size_t)b * KT + k0 + k] * 100.0f;
    }
    __syncthreads();
    if (tid < NC) {
        float acc[Bn];
        #pragma unroll
        for (int b = 0; b < Bn; ++b) acc[b] = 0.f;
        for (int kk = 0; kk < 96; ++kk) {
            float w = wC[(size_t)(k0 + kk) * NC + tid];  // coalesced across n
            #pragma unroll
            for (int b = 0; b < Bn; ++b) acc[b] += eS[b * 96 + kk] * w;  // LDS broadcast
        }
        #pragma unroll
        for (int b = 0; b < Bn; ++b) atomicAdd(&logits[b * NC + tid], acc[b]);
    }
}

extern "C" void kernel_launch(void* const* d_in, const int* in_sizes, int n_in,
                              void* d_out, int out_size, void* d_ws, size_t ws_size,
                              hipStream_t stream) {
    const float* f6 = (const float*)d_in[0];
    const float* f7 = (const float*)d_in[1];
    const float* wA = (const float*)d_in[2];
    const float* wC = (const float*)d_in[3];
    float* out = (float*)d_out;
    float* logits = out + LOGITS_OFF;
    float* attn = out + ATTN_OFF;
    float* emb = out + EMB_OFF;

    float* norm_acc = (float*)d_ws;                       // 32 floats
    float* part = (float*)((char*)d_ws + 128);            // (B,S,M,C) f32
    size_t need = 128 + (size_t)Bn * Sn * KT * sizeof(float);  // ~24 MB
    int partial = (ws_size >= need) ? 1 : 0;

    z_kernel<<<3072, 256, 0, stream>>>(out, norm_acc, !partial);
    f_kernel<<<Bn * Sn, 768, 0, stream>>>(f6, f7, wA, attn, part, emb, partial);
    r_kernel<<<Bn * 8, 256, 0, stream>>>(part, emb, norm_acc, partial);
    n_kernel<<<Bn * 8, 256, 0, stream>>>(emb, norm_acc);
    l_kernel<<<KT / 96, 256, 0, stream>>>(emb, wC, logits);
}